// Round 3
// baseline (372.674 us; speedup 1.0000x reference)
//
#include <hip/hip_runtime.h>
#include <hip/hip_bf16.h>

#define B_  2
#define L_  2048
#define D_  1024
#define H_  16
#define HD_ 64

typedef __bf16 bf16x8 __attribute__((ext_vector_type(8)));
typedef float  f32x4  __attribute__((ext_vector_type(4)));
using bf16_t = __hip_bfloat16;

static __device__ __forceinline__ f32x4 mfma16(bf16x8 a, bf16x8 b, f32x4 c) {
    return __builtin_amdgcn_mfma_f32_16x16x32_bf16(a, b, c, 0, 0, 0);
}

// async global->LDS, 16B per lane; LDS dest = wave-uniform base + lane*16
static __device__ __forceinline__ void gl16(const bf16_t* g, bf16_t* l) {
    __builtin_amdgcn_global_load_lds(
        (const __attribute__((address_space(1))) unsigned int*)g,
        (__attribute__((address_space(3))) unsigned int*)l, 16, 0, 0);
}

// ---- fp32 -> bf16 elementwise convert (x) ----
__global__ __launch_bounds__(256) void k_convert(const float* __restrict__ in,
                                                 bf16_t* __restrict__ out, int n8) {
    int idx = blockIdx.x * 256 + threadIdx.x;
    if (idx >= n8) return;
    const float4* p = (const float4*)in + (size_t)idx * 2;
    float4 a = p[0], b = p[1];
    union { bf16_t h[8]; bf16x8 v; } u;
    u.h[0] = __float2bfloat16(a.x); u.h[1] = __float2bfloat16(a.y);
    u.h[2] = __float2bfloat16(a.z); u.h[3] = __float2bfloat16(a.w);
    u.h[4] = __float2bfloat16(b.x); u.h[5] = __float2bfloat16(b.y);
    u.h[6] = __float2bfloat16(b.z); u.h[7] = __float2bfloat16(b.w);
    *(bf16x8*)(out + (size_t)idx * 8) = u.v;
}

// ---- fp32 W[k][n] -> bf16 Wt[n][k] (LDS-tiled transpose+convert) ----
__global__ __launch_bounds__(256) void k_transpose(const float* __restrict__ w,
                                                   bf16_t* __restrict__ wt) {
    __shared__ bf16_t tile[64][65];
    int t  = threadIdx.x;
    int kb = blockIdx.x * 64, nb = blockIdx.y * 64;
    int r  = t >> 4, c4 = (t & 15) * 4;
    #pragma unroll
    for (int it = 0; it < 4; ++it) {
        int kr = r + it * 16;
        float4 v = *(const float4*)&w[(size_t)(kb + kr) * D_ + nb + c4];
        tile[kr][c4 + 0] = __float2bfloat16(v.x);
        tile[kr][c4 + 1] = __float2bfloat16(v.y);
        tile[kr][c4 + 2] = __float2bfloat16(v.z);
        tile[kr][c4 + 3] = __float2bfloat16(v.w);
    }
    __syncthreads();
    #pragma unroll
    for (int it = 0; it < 4; ++it) {
        int nr = r + it * 16;
        union { bf16_t h[4]; unsigned long long u; } o;
        o.h[0] = tile[c4 + 0][nr];
        o.h[1] = tile[c4 + 1][nr];
        o.h[2] = tile[c4 + 2][nr];
        o.h[3] = tile[c4 + 3][nr];
        *(unsigned long long*)&wt[(size_t)(nb + nr) * D_ + kb + c4] = o.u;
    }
}

// ---- bf16 GEMM: C[M=4096][N=1024] = A[M][K] @ W[K][N] + bias, W given as Wt[n][k]
// staging via global_load_lds width=16.
// MODE 0: bf16 [B,H,L,HD]   MODE 1: bf16 [B,H,HD,L] (V^T)   MODE 2: fp32 row-major
template <int MODE>
__global__ __launch_bounds__(256) void k_gemm(const bf16_t* __restrict__ A,
                                              const bf16_t* __restrict__ Wt,
                                              const float* __restrict__ bias,
                                              void* __restrict__ outp) {
    __shared__ __align__(16) bf16_t Al[128][32];
    __shared__ __align__(16) bf16_t Bl[128][32];
    const int K = D_;
    int tid = threadIdx.x, lane = tid & 63, wid = tid >> 6;
    int m0 = blockIdx.y * 128, n0 = blockIdx.x * 128;
    int wm = (wid >> 1) * 64, wn = (wid & 1) * 64;
    int r16 = lane & 15, g = lane >> 4;
    int lrow = lane >> 2, lcol = (lane & 3) * 8;   // 4 lanes x 16B per 64B row
    f32x4 acc[4][4] = {};
    for (int kb = 0; kb < K; kb += 32) {
        __syncthreads();
        gl16(&A [(size_t)(m0 + wid * 32 + lrow) * K + kb + lcol],      &Al[wid * 32][0]);
        gl16(&A [(size_t)(m0 + wid * 32 + 16 + lrow) * K + kb + lcol], &Al[wid * 32 + 16][0]);
        gl16(&Wt[(size_t)(n0 + wid * 32 + lrow) * K + kb + lcol],      &Bl[wid * 32][0]);
        gl16(&Wt[(size_t)(n0 + wid * 32 + 16 + lrow) * K + kb + lcol], &Bl[wid * 32 + 16][0]);
        __syncthreads();
        bf16x8 af[4], bfr[4];
        #pragma unroll
        for (int i = 0; i < 4; ++i) af[i]  = *(const bf16x8*)&Al[wm + i * 16 + r16][g * 8];
        #pragma unroll
        for (int j = 0; j < 4; ++j) bfr[j] = *(const bf16x8*)&Bl[wn + j * 16 + r16][g * 8];
        #pragma unroll
        for (int i = 0; i < 4; ++i)
            #pragma unroll
            for (int j = 0; j < 4; ++j)
                acc[i][j] = mfma16(af[i], bfr[j], acc[i][j]);
    }
    #pragma unroll
    for (int i = 0; i < 4; ++i) {
        #pragma unroll
        for (int j = 0; j < 4; ++j) {
            int n = n0 + wn + j * 16 + r16;
            float bv = bias[n];
            #pragma unroll
            for (int e = 0; e < 4; ++e) {
                int m = m0 + wm + i * 16 + g * 4 + e;
                float v = acc[i][j][e] + bv;
                if (MODE == 2) {
                    ((float*)outp)[(size_t)m * D_ + n] = v;
                } else {
                    int b = m >> 11, l = m & (L_ - 1);
                    int h = n >> 6, hd = n & 63;
                    bf16_t* o = (bf16_t*)outp;
                    if (MODE == 0)
                        o[(((size_t)(b * H_ + h)) * L_ + l) * HD_ + hd] = __float2bfloat16(v);
                    else
                        o[(((size_t)(b * H_ + h)) * HD_ + hd) * L_ + l] = __float2bfloat16(v);
                }
            }
        }
    }
}

// ---- fused causal attention v3: swapped QK^T (mfma(K,Q)) ----
// D-layout: col=r16=q-row, row=g*4+e=4 consecutive keys -> float4 attn stores,
// 8B packed P-tile LDS writes, shuffle-free normalization in phase 2.
__global__ __launch_bounds__(128, 3) void k_attn(const bf16_t* __restrict__ Q,
                                                 const bf16_t* __restrict__ Kb,
                                                 const bf16_t* __restrict__ VT,
                                                 bf16_t* __restrict__ ctx,
                                                 float* __restrict__ attn) {
    __shared__ __align__(16) bf16_t plds[2][32][40];
    int tid = threadIdx.x, lane = tid & 63, wid = tid >> 6;
    int task = blockIdx.x * 2 + wid;
    int bh = task & 31;
    int qt = 63 - (task >> 5);          // heavy-first
    int b = bh >> 4, h = bh & 15;
    int qb = qt * 32;
    const int diag = qt;
    const bf16_t* Qh = Q  + (size_t)bh * L_ * HD_;
    const bf16_t* Kh = Kb + (size_t)bh * L_ * HD_;
    const bf16_t* Vh = VT + (size_t)bh * HD_ * L_;
    int r16 = lane & 15, g = lane >> 4;
    const float scale = 0.125f;

    bf16x8 q[2][2];
    #pragma unroll
    for (int p = 0; p < 2; ++p)
        #pragma unroll
        for (int hh = 0; hh < 2; ++hh)
            q[p][hh] = *(const bf16x8*)&Qh[(qb + p * 16 + r16) * HD_ + hh * 32 + g * 8];

    f32x4 ctxa[2][4] = {};
    float zsum[2] = {0.f, 0.f};

    bf16x8 kA[2][2], kB[2][2];

    auto LK = [&](bf16x8 (&kf)[2][2], int kt) {
        const bf16_t* base = Kh + (size_t)kt * 32 * HD_;
        #pragma unroll
        for (int s = 0; s < 2; ++s)
            #pragma unroll
            for (int hh = 0; hh < 2; ++hh)
                kf[s][hh] = *(const bf16x8*)&base[(s * 16 + r16) * HD_ + hh * 32 + g * 8];
    };

    // phase 1: Z + unnormalized PV
    auto p1step = [&](bf16x8 (&KF)[2][2], bf16x8 (&KFN)[2][2], int kt) {
        bf16x8 vf[4];
        const bf16_t* vbase = Vh + kt * 32 + g * 8;
        #pragma unroll
        for (int t = 0; t < 4; ++t)
            vf[t] = *(const bf16x8*)&vbase[(size_t)(t * 16 + r16) * L_];
        f32x4 sa[2][2];
        #pragma unroll
        for (int p = 0; p < 2; ++p)
            #pragma unroll
            for (int s = 0; s < 2; ++s) {
                f32x4 zz = {};
                sa[p][s] = mfma16(KF[s][1], q[p][1], mfma16(KF[s][0], q[p][0], zz));
            }
        if (kt < diag) LK(KFN, kt + 1);
        int kb = kt * 32;
        #pragma unroll
        for (int p = 0; p < 2; ++p) {
            int qrow = qb + p * 16 + r16;
            #pragma unroll
            for (int s = 0; s < 2; ++s) {
                union { bf16_t hv[4]; unsigned long long u; } pk;
                #pragma unroll
                for (int e = 0; e < 4; ++e) {
                    int key = kb + s * 16 + g * 4 + e;
                    float sc = sa[p][s][e] * scale;
                    sc = fminf(fmaxf(sc, -50.f), 50.f);
                    float ev = (key > qrow) ? 0.f : __expf(sc);
                    zsum[p] += ev;
                    pk.hv[e] = __float2bfloat16(ev);
                }
                *(unsigned long long*)&plds[wid][p * 16 + r16][s * 16 + g * 4] = pk.u;
            }
        }
        #pragma unroll
        for (int p = 0; p < 2; ++p) {
            bf16x8 pa = *(const bf16x8*)&plds[wid][p * 16 + r16][g * 8];
            #pragma unroll
            for (int t = 0; t < 4; ++t)
                ctxa[p][t] = mfma16(pa, vf[t], ctxa[p][t]);
        }
    };

    LK(kA, 0);
    for (int kt = 0;;) {
        p1step(kA, kB, kt); if (++kt > diag) break;
        p1step(kB, kA, kt); if (++kt > diag) break;
    }

    // Z-reduce across the 4 g-groups (same r16 -> same q-row)
    float invz[2];
    #pragma unroll
    for (int p = 0; p < 2; ++p) {
        float v = zsum[p];
        v += __shfl_xor(v, 16);
        v += __shfl_xor(v, 32);
        invz[p] = 1.f / v;
    }

    // normalized context -> ctx [B, L, D] bf16 (PV D-layout: row=g*4+e=q, col=r16=hd)
    #pragma unroll
    for (int p = 0; p < 2; ++p) {
        #pragma unroll
        for (int e = 0; e < 4; ++e) {
            float izq = __shfl(invz[p], g * 4 + e);   // z for q-row g*4+e
            int qrow = qb + p * 16 + g * 4 + e;
            #pragma unroll
            for (int t = 0; t < 4; ++t) {
                int col = h * HD_ + t * 16 + r16;
                ctx[((size_t)b * L_ + qrow) * D_ + col] =
                    __float2bfloat16(ctxa[p][t][e] * izq);
            }
        }
    }

    // phase 2: recompute scores, float4 attn stores (invz already per-lane: row=r16)
    auto p2step = [&](bf16x8 (&KF)[2][2], bf16x8 (&KFN)[2][2], int kt) {
        f32x4 sa[2][2];
        #pragma unroll
        for (int p = 0; p < 2; ++p)
            #pragma unroll
            for (int s = 0; s < 2; ++s) {
                f32x4 zz = {};
                sa[p][s] = mfma16(KF[s][1], q[p][1], mfma16(KF[s][0], q[p][0], zz));
            }
        if (kt < diag) LK(KFN, kt + 1);
        int kb = kt * 32;
        #pragma unroll
        for (int p = 0; p < 2; ++p) {
            int qrow = qb + p * 16 + r16;
            #pragma unroll
            for (int s = 0; s < 2; ++s) {
                float4 fv;
                float* fp = &fv.x;
                #pragma unroll
                for (int e = 0; e < 4; ++e) {
                    int key = kb + s * 16 + g * 4 + e;
                    float sc = sa[p][s][e] * scale;
                    sc = fminf(fmaxf(sc, -50.f), 50.f);
                    fp[e] = (key > qrow) ? 0.f : __expf(sc) * invz[p];
                }
                *(float4*)&attn[((size_t)bh * L_ + qrow) * L_ + kb + s * 16 + g * 4] = fv;
            }
        }
    };

    LK(kA, 0);
    for (int kt = 0;;) {
        p2step(kA, kB, kt); if (++kt > diag) break;
        p2step(kB, kA, kt); if (++kt > diag) break;
    }

    // zero-fill fully-masked tail
    int zs = (qt + 1) * 32;
    if (zs < L_) {
        float4 z4 = make_float4(0.f, 0.f, 0.f, 0.f);
        for (int r = 0; r < 32; ++r) {
            float* rowp = attn + ((size_t)bh * L_ + qb + r) * L_;
            for (int c = zs + lane * 4; c < L_; c += 256)
                *(float4*)&rowp[c] = z4;
        }
    }
}

extern "C" void kernel_launch(void* const* d_in, const int* in_sizes, int n_in,
                              void* d_out, int out_size, void* d_ws, size_t ws_size,
                              hipStream_t stream) {
    const float* x  = (const float*)d_in[0];
    const float* wq = (const float*)d_in[1];
    const float* bq = (const float*)d_in[2];
    const float* wk = (const float*)d_in[3];
    const float* bk = (const float*)d_in[4];
    const float* wv = (const float*)d_in[5];
    const float* bv = (const float*)d_in[6];
    const float* wo = (const float*)d_in[7];
    const float* bo = (const float*)d_in[8];

    char* ws = (char*)d_ws;
    bf16_t* xb   = (bf16_t*)(ws);
    bf16_t* wqt  = (bf16_t*)(ws + ( 8u << 20));
    bf16_t* wkt  = (bf16_t*)(ws + (10u << 20));
    bf16_t* wvt  = (bf16_t*)(ws + (12u << 20));
    bf16_t* wot  = (bf16_t*)(ws + (14u << 20));
    bf16_t* Qb   = (bf16_t*)(ws + (16u << 20));
    bf16_t* Kbuf = (bf16_t*)(ws + (24u << 20));
    bf16_t* VTb  = (bf16_t*)(ws + (32u << 20));
    bf16_t* ctxb = (bf16_t*)(ws + (40u << 20));

    float* out  = (float*)d_out;
    float* attn = out + (size_t)B_ * L_ * D_;

    k_convert<<<2048, 256, 0, stream>>>(x, xb, (B_ * L_ * D_) / 8);
    dim3 tg(16, 16);
    k_transpose<<<tg, 256, 0, stream>>>(wq, wqt);
    k_transpose<<<tg, 256, 0, stream>>>(wk, wkt);
    k_transpose<<<tg, 256, 0, stream>>>(wv, wvt);
    k_transpose<<<tg, 256, 0, stream>>>(wo, wot);

    dim3 gg(D_ / 128, (B_ * L_) / 128);
    k_gemm<0><<<gg, 256, 0, stream>>>(xb, wqt, bq, Qb);
    k_gemm<0><<<gg, 256, 0, stream>>>(xb, wkt, bk, Kbuf);
    k_gemm<1><<<gg, 256, 0, stream>>>(xb, wvt, bv, VTb);

    k_attn<<<1024, 128, 0, stream>>>(Qb, Kbuf, VTb, ctxb, attn);

    k_gemm<2><<<gg, 256, 0, stream>>>(ctxb, wot, bo, d_out);
}

// Round 4
// 287.676 us; speedup vs baseline: 1.2955x; 1.2955x over previous
//
#include <hip/hip_runtime.h>
#include <hip/hip_bf16.h>

#define B_  2
#define L_  2048
#define D_  1024
#define H_  16
#define HD_ 64

typedef __bf16 bf16x8 __attribute__((ext_vector_type(8)));
typedef float  f32x4  __attribute__((ext_vector_type(4)));
using bf16_t = __hip_bfloat16;

static __device__ __forceinline__ f32x4 mfma16(bf16x8 a, bf16x8 b, f32x4 c) {
    return __builtin_amdgcn_mfma_f32_16x16x32_bf16(a, b, c, 0, 0, 0);
}

// async global->LDS, 16B per lane; LDS dest = wave-uniform base + lane*16
static __device__ __forceinline__ void gl16(const bf16_t* g, bf16_t* l) {
    __builtin_amdgcn_global_load_lds(
        (const __attribute__((address_space(1))) unsigned int*)g,
        (__attribute__((address_space(3))) unsigned int*)l, 16, 0, 0);
}

// ---- fp32 -> bf16 elementwise convert (x) ----
__global__ __launch_bounds__(256) void k_convert(const float* __restrict__ in,
                                                 bf16_t* __restrict__ out, int n8) {
    int idx = blockIdx.x * 256 + threadIdx.x;
    if (idx >= n8) return;
    const float4* p = (const float4*)in + (size_t)idx * 2;
    float4 a = p[0], b = p[1];
    union { bf16_t h[8]; bf16x8 v; } u;
    u.h[0] = __float2bfloat16(a.x); u.h[1] = __float2bfloat16(a.y);
    u.h[2] = __float2bfloat16(a.z); u.h[3] = __float2bfloat16(a.w);
    u.h[4] = __float2bfloat16(b.x); u.h[5] = __float2bfloat16(b.y);
    u.h[6] = __float2bfloat16(b.z); u.h[7] = __float2bfloat16(b.w);
    *(bf16x8*)(out + (size_t)idx * 8) = u.v;
}

// ---- fp32 W[k][n] -> bf16 Wt[n][k] (LDS-tiled transpose+convert) ----
__global__ __launch_bounds__(256) void k_transpose(const float* __restrict__ w,
                                                   bf16_t* __restrict__ wt) {
    __shared__ bf16_t tile[64][65];
    int t  = threadIdx.x;
    int kb = blockIdx.x * 64, nb = blockIdx.y * 64;
    int r  = t >> 4, c4 = (t & 15) * 4;
    #pragma unroll
    for (int it = 0; it < 4; ++it) {
        int kr = r + it * 16;
        float4 v = *(const float4*)&w[(size_t)(kb + kr) * D_ + nb + c4];
        tile[kr][c4 + 0] = __float2bfloat16(v.x);
        tile[kr][c4 + 1] = __float2bfloat16(v.y);
        tile[kr][c4 + 2] = __float2bfloat16(v.z);
        tile[kr][c4 + 3] = __float2bfloat16(v.w);
    }
    __syncthreads();
    #pragma unroll
    for (int it = 0; it < 4; ++it) {
        int nr = r + it * 16;
        union { bf16_t h[4]; unsigned long long u; } o;
        o.h[0] = tile[c4 + 0][nr];
        o.h[1] = tile[c4 + 1][nr];
        o.h[2] = tile[c4 + 2][nr];
        o.h[3] = tile[c4 + 3][nr];
        *(unsigned long long*)&wt[(size_t)(nb + nr) * D_ + kb + c4] = o.u;
    }
}

// ---- merged QKV GEMM: z=0 -> Q [B,H,L,HD], z=1 -> K [B,H,L,HD], z=2 -> V^T [B,H,HD,L]
__global__ __launch_bounds__(256, 3) void k_gemm_qkv(
        const bf16_t* __restrict__ A,
        const bf16_t* __restrict__ Wq, const bf16_t* __restrict__ Wk, const bf16_t* __restrict__ Wv,
        const float* __restrict__ bq, const float* __restrict__ bk, const float* __restrict__ bv,
        bf16_t* __restrict__ Qo, bf16_t* __restrict__ Ko, bf16_t* __restrict__ Vo) {
    __shared__ __align__(16) bf16_t Al[128][32];
    __shared__ __align__(16) bf16_t Bl[128][32];
    const int K = D_;
    int z = blockIdx.z;
    const bf16_t* Wt = (z == 0) ? Wq : (z == 1) ? Wk : Wv;
    const float* bias = (z == 0) ? bq : (z == 1) ? bk : bv;
    bf16_t* outp      = (z == 0) ? Qo : (z == 1) ? Ko : Vo;
    int tid = threadIdx.x, lane = tid & 63, wid = tid >> 6;
    int m0 = blockIdx.y * 128, n0 = blockIdx.x * 128;
    int wm = (wid >> 1) * 64, wn = (wid & 1) * 64;
    int r16 = lane & 15, g = lane >> 4;
    int lrow = lane >> 2, lcol = (lane & 3) * 8;
    f32x4 acc[4][4] = {};
    for (int kb = 0; kb < K; kb += 32) {
        __syncthreads();
        gl16(&A [(size_t)(m0 + wid * 32 + lrow) * K + kb + lcol],      &Al[wid * 32][0]);
        gl16(&A [(size_t)(m0 + wid * 32 + 16 + lrow) * K + kb + lcol], &Al[wid * 32 + 16][0]);
        gl16(&Wt[(size_t)(n0 + wid * 32 + lrow) * K + kb + lcol],      &Bl[wid * 32][0]);
        gl16(&Wt[(size_t)(n0 + wid * 32 + 16 + lrow) * K + kb + lcol], &Bl[wid * 32 + 16][0]);
        __syncthreads();
        bf16x8 af[4], bfr[4];
        #pragma unroll
        for (int i = 0; i < 4; ++i) af[i]  = *(const bf16x8*)&Al[wm + i * 16 + r16][g * 8];
        #pragma unroll
        for (int j = 0; j < 4; ++j) bfr[j] = *(const bf16x8*)&Bl[wn + j * 16 + r16][g * 8];
        #pragma unroll
        for (int i = 0; i < 4; ++i)
            #pragma unroll
            for (int j = 0; j < 4; ++j)
                acc[i][j] = mfma16(af[i], bfr[j], acc[i][j]);
    }
    #pragma unroll
    for (int i = 0; i < 4; ++i) {
        #pragma unroll
        for (int j = 0; j < 4; ++j) {
            int n = n0 + wn + j * 16 + r16;
            float bv2 = bias[n];
            #pragma unroll
            for (int e = 0; e < 4; ++e) {
                int m = m0 + wm + i * 16 + g * 4 + e;
                float v = acc[i][j][e] + bv2;
                int b = m >> 11, l = m & (L_ - 1);
                int h = n >> 6, hd = n & 63;
                if (z != 2)
                    outp[(((size_t)(b * H_ + h)) * L_ + l) * HD_ + hd] = __float2bfloat16(v);
                else
                    outp[(((size_t)(b * H_ + h)) * HD_ + hd) * L_ + l] = __float2bfloat16(v);
            }
        }
    }
}

// ---- O-projection GEMM (fp32 out) ----
__global__ __launch_bounds__(256) void k_gemm_o(const bf16_t* __restrict__ A,
                                                const bf16_t* __restrict__ Wt,
                                                const float* __restrict__ bias,
                                                float* __restrict__ outp) {
    __shared__ __align__(16) bf16_t Al[128][32];
    __shared__ __align__(16) bf16_t Bl[128][32];
    const int K = D_;
    int tid = threadIdx.x, lane = tid & 63, wid = tid >> 6;
    int m0 = blockIdx.y * 128, n0 = blockIdx.x * 128;
    int wm = (wid >> 1) * 64, wn = (wid & 1) * 64;
    int r16 = lane & 15, g = lane >> 4;
    int lrow = lane >> 2, lcol = (lane & 3) * 8;
    f32x4 acc[4][4] = {};
    for (int kb = 0; kb < K; kb += 32) {
        __syncthreads();
        gl16(&A [(size_t)(m0 + wid * 32 + lrow) * K + kb + lcol],      &Al[wid * 32][0]);
        gl16(&A [(size_t)(m0 + wid * 32 + 16 + lrow) * K + kb + lcol], &Al[wid * 32 + 16][0]);
        gl16(&Wt[(size_t)(n0 + wid * 32 + lrow) * K + kb + lcol],      &Bl[wid * 32][0]);
        gl16(&Wt[(size_t)(n0 + wid * 32 + 16 + lrow) * K + kb + lcol], &Bl[wid * 32 + 16][0]);
        __syncthreads();
        bf16x8 af[4], bfr[4];
        #pragma unroll
        for (int i = 0; i < 4; ++i) af[i]  = *(const bf16x8*)&Al[wm + i * 16 + r16][g * 8];
        #pragma unroll
        for (int j = 0; j < 4; ++j) bfr[j] = *(const bf16x8*)&Bl[wn + j * 16 + r16][g * 8];
        #pragma unroll
        for (int i = 0; i < 4; ++i)
            #pragma unroll
            for (int j = 0; j < 4; ++j)
                acc[i][j] = mfma16(af[i], bfr[j], acc[i][j]);
    }
    #pragma unroll
    for (int i = 0; i < 4; ++i)
        #pragma unroll
        for (int j = 0; j < 4; ++j) {
            int n = n0 + wn + j * 16 + r16;
            float bv = bias[n];
            #pragma unroll
            for (int e = 0; e < 4; ++e) {
                int m = m0 + wm + i * 16 + g * 4 + e;
                outp[(size_t)m * D_ + n] = acc[i][j][e] + bv;
            }
        }
}

// ---- fused causal attention v4 ----
// XCD-aware task map: xcd = bid&7 owns heads {xcd+8k}; per-CU single head.
// Phase1: Z + unnorm PV, K and V prefetched one kt step ahead.
// Phase2: recompute, normalize, LDS f32 transpose -> 8-row x 128B coalesced stores.
__global__ __launch_bounds__(128, 2) void k_attn(const bf16_t* __restrict__ Q,
                                                 const bf16_t* __restrict__ Kb,
                                                 const bf16_t* __restrict__ VT,
                                                 bf16_t* __restrict__ ctx,
                                                 float* __restrict__ attn) {
    __shared__ __align__(16) bf16_t plds[2][32][40];
    __shared__ __align__(16) float  pf32[2][32][36];
    int tid = threadIdx.x, lane = tid & 63, wid = tid >> 6;
    int bid = blockIdx.x;
    int idx = bid >> 3;
    int bh  = (bid & 7) + 8 * (idx & 3);           // 4 heads per XCD
    int qt  = 63 - (2 * (idx >> 2) + wid);         // heavy-first, 2 qt per block
    int b = bh >> 4, h = bh & 15;
    int qb = qt * 32;
    const int diag = qt;
    const bf16_t* Qh = Q  + (size_t)bh * L_ * HD_;
    const bf16_t* Kh = Kb + (size_t)bh * L_ * HD_;
    const bf16_t* Vh = VT + (size_t)bh * HD_ * L_;
    int r16 = lane & 15, g = lane >> 4;
    const float scale = 0.125f;

    bf16x8 q[2][2];
    #pragma unroll
    for (int p = 0; p < 2; ++p)
        #pragma unroll
        for (int hh = 0; hh < 2; ++hh)
            q[p][hh] = *(const bf16x8*)&Qh[(qb + p * 16 + r16) * HD_ + hh * 32 + g * 8];

    f32x4 ctxa[2][4] = {};
    float zsum[2] = {0.f, 0.f};

    bf16x8 kA[2][2], kB[2][2], vA[4], vB[4];

    auto LK = [&](bf16x8 (&kf)[2][2], int kt) {
        const bf16_t* base = Kh + (size_t)kt * 32 * HD_;
        #pragma unroll
        for (int s = 0; s < 2; ++s)
            #pragma unroll
            for (int hh = 0; hh < 2; ++hh)
                kf[s][hh] = *(const bf16x8*)&base[(s * 16 + r16) * HD_ + hh * 32 + g * 8];
    };
    auto LV = [&](bf16x8 (&vf)[4], int kt) {
        const bf16_t* vbase = Vh + kt * 32 + g * 8;
        #pragma unroll
        for (int t = 0; t < 4; ++t)
            vf[t] = *(const bf16x8*)&vbase[(size_t)(t * 16 + r16) * L_];
    };

    // phase 1: Z + unnormalized PV
    auto p1step = [&](bf16x8 (&KF)[2][2], bf16x8 (&KFN)[2][2],
                      bf16x8 (&VF)[4],    bf16x8 (&VFN)[4], int kt) {
        f32x4 sa[2][2];
        #pragma unroll
        for (int p = 0; p < 2; ++p)
            #pragma unroll
            for (int s = 0; s < 2; ++s) {
                f32x4 zz = {};
                sa[p][s] = mfma16(KF[s][1], q[p][1], mfma16(KF[s][0], q[p][0], zz));
            }
        if (kt < diag) { LK(KFN, kt + 1); LV(VFN, kt + 1); }
        int kb = kt * 32;
        #pragma unroll
        for (int p = 0; p < 2; ++p) {
            int qrow = qb + p * 16 + r16;
            #pragma unroll
            for (int s = 0; s < 2; ++s) {
                union { bf16_t hv[4]; unsigned long long u; } pk;
                #pragma unroll
                for (int e = 0; e < 4; ++e) {
                    int key = kb + s * 16 + g * 4 + e;
                    float sc = sa[p][s][e] * scale;
                    sc = fminf(fmaxf(sc, -50.f), 50.f);
                    float ev = (key > qrow) ? 0.f : __expf(sc);
                    zsum[p] += ev;
                    pk.hv[e] = __float2bfloat16(ev);
                }
                *(unsigned long long*)&plds[wid][p * 16 + r16][s * 16 + g * 4] = pk.u;
            }
        }
        #pragma unroll
        for (int p = 0; p < 2; ++p) {
            bf16x8 pa = *(const bf16x8*)&plds[wid][p * 16 + r16][g * 8];
            #pragma unroll
            for (int t = 0; t < 4; ++t)
                ctxa[p][t] = mfma16(pa, VF[t], ctxa[p][t]);
        }
    };

    LK(kA, 0); LV(vA, 0);
    for (int kt = 0;;) {
        p1step(kA, kB, vA, vB, kt); if (++kt > diag) break;
        p1step(kB, kA, vB, vA, kt); if (++kt > diag) break;
    }

    // Z-reduce across the 4 g-groups (same r16 -> same q-row)
    float invz[2];
    #pragma unroll
    for (int p = 0; p < 2; ++p) {
        float v = zsum[p];
        v += __shfl_xor(v, 16);
        v += __shfl_xor(v, 32);
        invz[p] = 1.f / v;
    }

    // normalized context -> ctx [B, L, D] bf16 (PV D-layout: row=g*4+e=q, col=r16=hd)
    #pragma unroll
    for (int p = 0; p < 2; ++p) {
        #pragma unroll
        for (int e = 0; e < 4; ++e) {
            float izq = __shfl(invz[p], g * 4 + e);
            int qrow = qb + p * 16 + g * 4 + e;
            #pragma unroll
            for (int t = 0; t < 4; ++t) {
                int col = h * HD_ + t * 16 + r16;
                ctx[((size_t)b * L_ + qrow) * D_ + col] =
                    __float2bfloat16(ctxa[p][t][e] * izq);
            }
        }
    }

    // phase 2: recompute scores, normalize, coalesced store via LDS transpose
    auto p2step = [&](bf16x8 (&KF)[2][2], bf16x8 (&KFN)[2][2], int kt) {
        f32x4 sa[2][2];
        #pragma unroll
        for (int p = 0; p < 2; ++p)
            #pragma unroll
            for (int s = 0; s < 2; ++s) {
                f32x4 zz = {};
                sa[p][s] = mfma16(KF[s][1], q[p][1], mfma16(KF[s][0], q[p][0], zz));
            }
        if (kt < diag) LK(KFN, kt + 1);
        int kb = kt * 32;
        #pragma unroll
        for (int p = 0; p < 2; ++p) {
            int qrow = qb + p * 16 + r16;
            #pragma unroll
            for (int s = 0; s < 2; ++s) {
                float4 fv;
                float* fp = &fv.x;
                #pragma unroll
                for (int e = 0; e < 4; ++e) {
                    int key = kb + s * 16 + g * 4 + e;
                    float sc = sa[p][s][e] * scale;
                    sc = fminf(fmaxf(sc, -50.f), 50.f);
                    fp[e] = (key > qrow) ? 0.f : __expf(sc) * invz[p];
                }
                *(float4*)&pf32[wid][p * 16 + r16][s * 16 + g * 4] = fv;
            }
        }
        // transposed coalesced store: per instr 8 rows x 128B (full L2 lines)
        #pragma unroll
        for (int j = 0; j < 4; ++j) {
            int row = j * 8 + (lane >> 3);
            float4 t = *(const float4*)&pf32[wid][row][(lane & 7) * 4];
            *(float4*)&attn[((size_t)bh * L_ + qb + row) * L_ + kb + (lane & 7) * 4] = t;
        }
    };

    LK(kA, 0);
    for (int kt = 0;;) {
        p2step(kA, kB, kt); if (++kt > diag) break;
        p2step(kB, kA, kt); if (++kt > diag) break;
    }

    // zero-fill fully-masked tail
    int zs = (qt + 1) * 32;
    if (zs < L_) {
        float4 z4 = make_float4(0.f, 0.f, 0.f, 0.f);
        for (int r = 0; r < 32; ++r) {
            float* rowp = attn + ((size_t)bh * L_ + qb + r) * L_;
            for (int c = zs + lane * 4; c < L_; c += 256)
                *(float4*)&rowp[c] = z4;
        }
    }
}

extern "C" void kernel_launch(void* const* d_in, const int* in_sizes, int n_in,
                              void* d_out, int out_size, void* d_ws, size_t ws_size,
                              hipStream_t stream) {
    const float* x  = (const float*)d_in[0];
    const float* wq = (const float*)d_in[1];
    const float* bq = (const float*)d_in[2];
    const float* wk = (const float*)d_in[3];
    const float* bk = (const float*)d_in[4];
    const float* wv = (const float*)d_in[5];
    const float* bv = (const float*)d_in[6];
    const float* wo = (const float*)d_in[7];
    const float* bo = (const float*)d_in[8];

    char* ws = (char*)d_ws;
    bf16_t* xb   = (bf16_t*)(ws);
    bf16_t* wqt  = (bf16_t*)(ws + ( 8u << 20));
    bf16_t* wkt  = (bf16_t*)(ws + (10u << 20));
    bf16_t* wvt  = (bf16_t*)(ws + (12u << 20));
    bf16_t* wot  = (bf16_t*)(ws + (14u << 20));
    bf16_t* Qb   = (bf16_t*)(ws + (16u << 20));
    bf16_t* Kbuf = (bf16_t*)(ws + (24u << 20));
    bf16_t* VTb  = (bf16_t*)(ws + (32u << 20));
    bf16_t* ctxb = (bf16_t*)(ws + (40u << 20));

    float* out  = (float*)d_out;
    float* attn = out + (size_t)B_ * L_ * D_;

    k_convert<<<2048, 256, 0, stream>>>(x, xb, (B_ * L_ * D_) / 8);
    dim3 tg(16, 16);
    k_transpose<<<tg, 256, 0, stream>>>(wq, wqt);
    k_transpose<<<tg, 256, 0, stream>>>(wk, wkt);
    k_transpose<<<tg, 256, 0, stream>>>(wv, wvt);
    k_transpose<<<tg, 256, 0, stream>>>(wo, wot);

    dim3 g3(D_ / 128, (B_ * L_) / 128, 3);
    k_gemm_qkv<<<g3, 256, 0, stream>>>(xb, wqt, wkt, wvt, bq, bk, bv, Qb, Kbuf, VTb);

    k_attn<<<1024, 128, 0, stream>>>(Qb, Kbuf, VTb, ctxb, attn);

    dim3 gg(D_ / 128, (B_ * L_) / 128);
    k_gemm_o<<<gg, 256, 0, stream>>>(ctxb, wot, bo, (float*)d_out);
}

// Round 5
// 262.265 us; speedup vs baseline: 1.4210x; 1.0969x over previous
//
#include <hip/hip_runtime.h>
#include <hip/hip_bf16.h>

#define B_  2
#define L_  2048
#define D_  1024
#define H_  16
#define HD_ 64

typedef __bf16 bf16x8 __attribute__((ext_vector_type(8)));
typedef float  f32x4  __attribute__((ext_vector_type(4)));
using bf16_t = __hip_bfloat16;

static __device__ __forceinline__ f32x4 mfma16(bf16x8 a, bf16x8 b, f32x4 c) {
    return __builtin_amdgcn_mfma_f32_16x16x32_bf16(a, b, c, 0, 0, 0);
}

// async global->LDS, 16B per lane; LDS dest = wave-uniform base + lane*16
static __device__ __forceinline__ void gl16(const bf16_t* g, bf16_t* l) {
    __builtin_amdgcn_global_load_lds(
        (const __attribute__((address_space(1))) unsigned int*)g,
        (__attribute__((address_space(3))) unsigned int*)l, 16, 0, 0);
}

// ---- fp32 -> bf16 elementwise convert (x) ----
__global__ __launch_bounds__(256) void k_convert(const float* __restrict__ in,
                                                 bf16_t* __restrict__ out, int n8) {
    int idx = blockIdx.x * 256 + threadIdx.x;
    if (idx >= n8) return;
    const float4* p = (const float4*)in + (size_t)idx * 2;
    float4 a = p[0], b = p[1];
    union { bf16_t h[8]; bf16x8 v; } u;
    u.h[0] = __float2bfloat16(a.x); u.h[1] = __float2bfloat16(a.y);
    u.h[2] = __float2bfloat16(a.z); u.h[3] = __float2bfloat16(a.w);
    u.h[4] = __float2bfloat16(b.x); u.h[5] = __float2bfloat16(b.y);
    u.h[6] = __float2bfloat16(b.z); u.h[7] = __float2bfloat16(b.w);
    *(bf16x8*)(out + (size_t)idx * 8) = u.v;
}

// ---- fp32 W[k][n] -> bf16 Wt[n][k], all 4 weights in one launch (z selects) ----
__global__ __launch_bounds__(256) void k_transpose4(
        const float* __restrict__ w0, const float* __restrict__ w1,
        const float* __restrict__ w2, const float* __restrict__ w3,
        bf16_t* __restrict__ t0, bf16_t* __restrict__ t1,
        bf16_t* __restrict__ t2, bf16_t* __restrict__ t3) {
    __shared__ bf16_t tile[64][65];
    int z = blockIdx.z;
    const float* w = (z == 0) ? w0 : (z == 1) ? w1 : (z == 2) ? w2 : w3;
    bf16_t* wt     = (z == 0) ? t0 : (z == 1) ? t1 : (z == 2) ? t2 : t3;
    int t  = threadIdx.x;
    int kb = blockIdx.x * 64, nb = blockIdx.y * 64;
    int r  = t >> 4, c4 = (t & 15) * 4;
    #pragma unroll
    for (int it = 0; it < 4; ++it) {
        int kr = r + it * 16;
        float4 v = *(const float4*)&w[(size_t)(kb + kr) * D_ + nb + c4];
        tile[kr][c4 + 0] = __float2bfloat16(v.x);
        tile[kr][c4 + 1] = __float2bfloat16(v.y);
        tile[kr][c4 + 2] = __float2bfloat16(v.z);
        tile[kr][c4 + 3] = __float2bfloat16(v.w);
    }
    __syncthreads();
    #pragma unroll
    for (int it = 0; it < 4; ++it) {
        int nr = r + it * 16;
        union { bf16_t h[4]; unsigned long long u; } o;
        o.h[0] = tile[c4 + 0][nr];
        o.h[1] = tile[c4 + 1][nr];
        o.h[2] = tile[c4 + 2][nr];
        o.h[3] = tile[c4 + 3][nr];
        *(unsigned long long*)&wt[(size_t)(nb + nr) * D_ + kb + c4] = o.u;
    }
}

// ---- merged QKV GEMM: z=0 -> Q [B,H,L,HD], z=1 -> K [B,H,L,HD], z=2 -> V^T [B,H,HD,L]
__global__ __launch_bounds__(256, 3) void k_gemm_qkv(
        const bf16_t* __restrict__ A,
        const bf16_t* __restrict__ Wq, const bf16_t* __restrict__ Wk, const bf16_t* __restrict__ Wv,
        const float* __restrict__ bq, const float* __restrict__ bk, const float* __restrict__ bv,
        bf16_t* __restrict__ Qo, bf16_t* __restrict__ Ko, bf16_t* __restrict__ Vo) {
    __shared__ __align__(16) bf16_t Al[128][32];
    __shared__ __align__(16) bf16_t Bl[128][32];
    const int K = D_;
    int z = blockIdx.z;
    const bf16_t* Wt = (z == 0) ? Wq : (z == 1) ? Wk : Wv;
    const float* bias = (z == 0) ? bq : (z == 1) ? bk : bv;
    bf16_t* outp      = (z == 0) ? Qo : (z == 1) ? Ko : Vo;
    int tid = threadIdx.x, lane = tid & 63, wid = tid >> 6;
    int m0 = blockIdx.y * 128, n0 = blockIdx.x * 128;
    int wm = (wid >> 1) * 64, wn = (wid & 1) * 64;
    int r16 = lane & 15, g = lane >> 4;
    int lrow = lane >> 2, lcol = (lane & 3) * 8;
    f32x4 acc[4][4] = {};
    for (int kb = 0; kb < K; kb += 32) {
        __syncthreads();
        gl16(&A [(size_t)(m0 + wid * 32 + lrow) * K + kb + lcol],      &Al[wid * 32][0]);
        gl16(&A [(size_t)(m0 + wid * 32 + 16 + lrow) * K + kb + lcol], &Al[wid * 32 + 16][0]);
        gl16(&Wt[(size_t)(n0 + wid * 32 + lrow) * K + kb + lcol],      &Bl[wid * 32][0]);
        gl16(&Wt[(size_t)(n0 + wid * 32 + 16 + lrow) * K + kb + lcol], &Bl[wid * 32 + 16][0]);
        __syncthreads();
        bf16x8 af[4], bfr[4];
        #pragma unroll
        for (int i = 0; i < 4; ++i) af[i]  = *(const bf16x8*)&Al[wm + i * 16 + r16][g * 8];
        #pragma unroll
        for (int j = 0; j < 4; ++j) bfr[j] = *(const bf16x8*)&Bl[wn + j * 16 + r16][g * 8];
        #pragma unroll
        for (int i = 0; i < 4; ++i)
            #pragma unroll
            for (int j = 0; j < 4; ++j)
                acc[i][j] = mfma16(af[i], bfr[j], acc[i][j]);
    }
    #pragma unroll
    for (int i = 0; i < 4; ++i) {
        #pragma unroll
        for (int j = 0; j < 4; ++j) {
            int n = n0 + wn + j * 16 + r16;
            float bv2 = bias[n];
            #pragma unroll
            for (int e = 0; e < 4; ++e) {
                int m = m0 + wm + i * 16 + g * 4 + e;
                float v = acc[i][j][e] + bv2;
                int b = m >> 11, l = m & (L_ - 1);
                int h = n >> 6, hd = n & 63;
                if (z != 2)
                    outp[(((size_t)(b * H_ + h)) * L_ + l) * HD_ + hd] = __float2bfloat16(v);
                else
                    outp[(((size_t)(b * H_ + h)) * HD_ + hd) * L_ + l] = __float2bfloat16(v);
            }
        }
    }
}

// ---- O-projection GEMM, 128x64 tiles (512 blocks = 2/CU) ----
__global__ __launch_bounds__(256, 2) void k_gemm_o(const bf16_t* __restrict__ A,
                                                   const bf16_t* __restrict__ Wt,
                                                   const float* __restrict__ bias,
                                                   float* __restrict__ outp) {
    __shared__ __align__(16) bf16_t Al[128][32];
    __shared__ __align__(16) bf16_t Bl[64][32];
    const int K = D_;
    int tid = threadIdx.x, lane = tid & 63, wid = tid >> 6;
    int m0 = blockIdx.y * 128, n0 = blockIdx.x * 64;
    int wm = (wid >> 1) * 64, wn = (wid & 1) * 32;
    int r16 = lane & 15, g = lane >> 4;
    int lrow = lane >> 2, lcol = (lane & 3) * 8;
    f32x4 acc[4][2] = {};
    for (int kb = 0; kb < K; kb += 32) {
        __syncthreads();
        gl16(&A [(size_t)(m0 + wid * 32 + lrow) * K + kb + lcol],      &Al[wid * 32][0]);
        gl16(&A [(size_t)(m0 + wid * 32 + 16 + lrow) * K + kb + lcol], &Al[wid * 32 + 16][0]);
        gl16(&Wt[(size_t)(n0 + wid * 16 + lrow) * K + kb + lcol],      &Bl[wid * 16][0]);
        __syncthreads();
        bf16x8 af[4], bfr[2];
        #pragma unroll
        for (int i = 0; i < 4; ++i) af[i]  = *(const bf16x8*)&Al[wm + i * 16 + r16][g * 8];
        #pragma unroll
        for (int j = 0; j < 2; ++j) bfr[j] = *(const bf16x8*)&Bl[wn + j * 16 + r16][g * 8];
        #pragma unroll
        for (int i = 0; i < 4; ++i)
            #pragma unroll
            for (int j = 0; j < 2; ++j)
                acc[i][j] = mfma16(af[i], bfr[j], acc[i][j]);
    }
    #pragma unroll
    for (int i = 0; i < 4; ++i)
        #pragma unroll
        for (int j = 0; j < 2; ++j) {
            int n = n0 + wn + j * 16 + r16;
            float bv = bias[n];
            #pragma unroll
            for (int e = 0; e < 4; ++e) {
                int m = m0 + wm + i * 16 + g * 4 + e;
                outp[(size_t)m * D_ + n] = acc[i][j][e] + bv;
            }
        }
}

// ---- fused causal attention v5: shared-LDS K/V staging ----
// block = 64 q-rows (2 waves x 32), one (bh, qt64). K/V double-buffered in LDS via
// global_load_lds (K with XOR chunk swizzle: src-swizzled, dest linear, read-swizzled).
// 1 barrier per kt step. XCD-aware: xcd owns 4 heads.
__global__ __launch_bounds__(128, 3) void k_attn(const bf16_t* __restrict__ Q,
                                                 const bf16_t* __restrict__ Kb,
                                                 const bf16_t* __restrict__ VT,
                                                 bf16_t* __restrict__ ctx,
                                                 float* __restrict__ attn) {
    __shared__ __align__(16) bf16_t K_lds[2][32][64];
    __shared__ __align__(16) bf16_t V_lds[2][64][32];
    __shared__ __align__(16) char   pbuf[2][4608];   // per-wave: plds (p1) / pf32 (p2)

    int tid = threadIdx.x, lane = tid & 63, wid = tid >> 6;
    int bid = blockIdx.x;
    int j   = bid >> 3;
    int bh  = (bid & 7) + 8 * (j & 3);     // 4 heads per XCD
    int qt64 = 31 - (j >> 2);              // heavy-first
    int b = bh >> 4, h = bh & 15;
    int qb = qt64 * 64;
    const int diag = 2 * qt64 + 1;         // kt strips 0..diag (32 keys each)
    const bf16_t* Qh = Q  + (size_t)bh * L_ * HD_;
    const bf16_t* Kh = Kb + (size_t)bh * L_ * HD_;
    const bf16_t* Vh = VT + (size_t)bh * HD_ * L_;
    int r16 = lane & 15, g = lane >> 4;
    const float scale2 = 0.125f * 1.44269504088896340736f;  // /8 * log2(e)
    const float clamp2 = 50.0f * 1.44269504088896340736f;

    bf16_t (*plds)[40] = (bf16_t(*)[40])pbuf[wid];
    float  (*pf32)[36] = (float (*)[36])pbuf[wid];

    int qrow0 = qb + wid * 32;             // this wave's first q-row

    bf16x8 q[2][2];
    #pragma unroll
    for (int p = 0; p < 2; ++p)
        #pragma unroll
        for (int hh = 0; hh < 2; ++hh)
            q[p][hh] = *(const bf16x8*)&Qh[(qrow0 + p * 16 + r16) * HD_ + hh * 32 + g * 8];

    // staging: K rows swizzled at source (chunk ^= row&7), LDS linear; V linear.
    int l = lane;
    int krow = l >> 3, kch = (l & 7) ^ (l >> 3);        // within 8-row K group
    int vrow = l >> 2, vch = l & 3;                     // within 16-row V group
    auto STAGE_K = [&](int kt1, int nxt) {
        #pragma unroll
        for (int i = 0; i < 2; ++i) {
            int ii = wid * 2 + i;
            gl16(&Kh[(size_t)(kt1 * 32 + 8 * ii + krow) * 64 + kch * 8], &K_lds[nxt][8 * ii][0]);
        }
    };
    auto STAGE_V = [&](int kt1, int nxt) {
        #pragma unroll
        for (int i = 0; i < 2; ++i) {
            int ii = wid * 2 + i;
            gl16(&Vh[(size_t)(16 * ii + vrow) * L_ + kt1 * 32 + vch * 8], &V_lds[nxt][16 * ii][0]);
        }
    };

    f32x4 ctxa[2][4] = {};
    float zsum[2] = {0.f, 0.f};

    // ---- phase 1: Z + unnormalized PV ----
    STAGE_K(0, 0); STAGE_V(0, 0);
    int cur = 0;
    for (int kt = 0; kt <= diag; ++kt) {
        __syncthreads();                    // drains vmcnt -> buf[cur] ready
        int nxt = cur ^ 1;
        if (kt < diag) { STAGE_K(kt + 1, nxt); STAGE_V(kt + 1, nxt); }
        bf16x8 kf[2][2], vf[4];
        #pragma unroll
        for (int s = 0; s < 2; ++s)
            #pragma unroll
            for (int hh = 0; hh < 2; ++hh)
                kf[s][hh] = *(const bf16x8*)&K_lds[cur][s * 16 + r16][((hh * 4 + g) ^ (r16 & 7)) * 8];
        #pragma unroll
        for (int t = 0; t < 4; ++t)
            vf[t] = *(const bf16x8*)&V_lds[cur][t * 16 + r16][g * 8];
        f32x4 sa[2][2];
        #pragma unroll
        for (int p = 0; p < 2; ++p)
            #pragma unroll
            for (int s = 0; s < 2; ++s) {
                f32x4 zz = {};
                sa[p][s] = mfma16(kf[s][1], q[p][1], mfma16(kf[s][0], q[p][0], zz));
            }
        int kb = kt * 32;
        #pragma unroll
        for (int p = 0; p < 2; ++p) {
            int qrow = qrow0 + p * 16 + r16;
            #pragma unroll
            for (int s = 0; s < 2; ++s) {
                union { bf16_t hv[4]; unsigned long long u; } pk;
                #pragma unroll
                for (int e = 0; e < 4; ++e) {
                    int key = kb + s * 16 + g * 4 + e;
                    float sc = sa[p][s][e] * scale2;
                    sc = fminf(fmaxf(sc, -clamp2), clamp2);
                    float ev = (key > qrow) ? 0.f : exp2f(sc);
                    zsum[p] += ev;
                    pk.hv[e] = __float2bfloat16(ev);
                }
                *(unsigned long long*)&plds[p * 16 + r16][s * 16 + g * 4] = pk.u;
            }
        }
        #pragma unroll
        for (int p = 0; p < 2; ++p) {
            bf16x8 pa = *(const bf16x8*)&plds[p * 16 + r16][g * 8];
            #pragma unroll
            for (int t = 0; t < 4; ++t)
                ctxa[p][t] = mfma16(pa, vf[t], ctxa[p][t]);
        }
        cur = nxt;
    }

    // Z-reduce across the 4 g-groups (same r16 -> same q-row)
    float invz[2];
    #pragma unroll
    for (int p = 0; p < 2; ++p) {
        float v = zsum[p];
        v += __shfl_xor(v, 16);
        v += __shfl_xor(v, 32);
        invz[p] = 1.f / v;
    }

    // normalized context -> ctx [B, L, D] bf16 (PV D-layout: row=g*4+e=q, col=r16=hd)
    #pragma unroll
    for (int p = 0; p < 2; ++p) {
        #pragma unroll
        for (int e = 0; e < 4; ++e) {
            float izq = __shfl(invz[p], g * 4 + e);
            int qrow = qrow0 + p * 16 + g * 4 + e;
            #pragma unroll
            for (int t = 0; t < 4; ++t) {
                int col = h * HD_ + t * 16 + r16;
                ctx[((size_t)b * L_ + qrow) * D_ + col] =
                    __float2bfloat16(ctxa[p][t][e] * izq);
            }
        }
    }

    // ---- phase 2: recompute scores, normalize, coalesced attn stores ----
    __syncthreads();                        // p1 done with K_lds/V_lds in all waves
    STAGE_K(0, 0);
    cur = 0;
    for (int kt = 0; kt <= diag; ++kt) {
        __syncthreads();
        int nxt = cur ^ 1;
        if (kt < diag) STAGE_K(kt + 1, nxt);
        bf16x8 kf[2][2];
        #pragma unroll
        for (int s = 0; s < 2; ++s)
            #pragma unroll
            for (int hh = 0; hh < 2; ++hh)
                kf[s][hh] = *(const bf16x8*)&K_lds[cur][s * 16 + r16][((hh * 4 + g) ^ (r16 & 7)) * 8];
        f32x4 sa[2][2];
        #pragma unroll
        for (int p = 0; p < 2; ++p)
            #pragma unroll
            for (int s = 0; s < 2; ++s) {
                f32x4 zz = {};
                sa[p][s] = mfma16(kf[s][1], q[p][1], mfma16(kf[s][0], q[p][0], zz));
            }
        int kb = kt * 32;
        #pragma unroll
        for (int p = 0; p < 2; ++p) {
            int qrow = qrow0 + p * 16 + r16;
            #pragma unroll
            for (int s = 0; s < 2; ++s) {
                float4 fv;
                float* fp = &fv.x;
                #pragma unroll
                for (int e = 0; e < 4; ++e) {
                    int key = kb + s * 16 + g * 4 + e;
                    float sc = sa[p][s][e] * scale2;
                    sc = fminf(fmaxf(sc, -clamp2), clamp2);
                    fp[e] = (key > qrow) ? 0.f : exp2f(sc) * invz[p];
                }
                *(float4*)&pf32[p * 16 + r16][s * 16 + g * 4] = fv;
            }
        }
        // transposed coalesced store: per instr 8 rows x 128B (full L2 lines)
        #pragma unroll
        for (int jj = 0; jj < 4; ++jj) {
            int row = jj * 8 + (lane >> 3);
            float4 t = *(const float4*)&pf32[row][(lane & 7) * 4];
            *(float4*)&attn[((size_t)bh * L_ + qrow0 + row) * L_ + kb + (lane & 7) * 4] = t;
        }
        cur = nxt;
    }

    // zero-fill fully-masked tail (this wave's 32 rows, cols >= qb+64)
    int zs = qb + 64;
    if (zs < L_) {
        float4 z4 = make_float4(0.f, 0.f, 0.f, 0.f);
        for (int r = 0; r < 32; ++r) {
            float* rowp = attn + ((size_t)bh * L_ + qrow0 + r) * L_;
            for (int c = zs + lane * 4; c < L_; c += 256)
                *(float4*)&rowp[c] = z4;
        }
    }
}

extern "C" void kernel_launch(void* const* d_in, const int* in_sizes, int n_in,
                              void* d_out, int out_size, void* d_ws, size_t ws_size,
                              hipStream_t stream) {
    const float* x  = (const float*)d_in[0];
    const float* wq = (const float*)d_in[1];
    const float* bq = (const float*)d_in[2];
    const float* wk = (const float*)d_in[3];
    const float* bk = (const float*)d_in[4];
    const float* wv = (const float*)d_in[5];
    const float* bv = (const float*)d_in[6];
    const float* wo = (const float*)d_in[7];
    const float* bo = (const float*)d_in[8];

    char* ws = (char*)d_ws;
    bf16_t* xb   = (bf16_t*)(ws);
    bf16_t* wqt  = (bf16_t*)(ws + ( 8u << 20));
    bf16_t* wkt  = (bf16_t*)(ws + (10u << 20));
    bf16_t* wvt  = (bf16_t*)(ws + (12u << 20));
    bf16_t* wot  = (bf16_t*)(ws + (14u << 20));
    bf16_t* Qb   = (bf16_t*)(ws + (16u << 20));
    bf16_t* Kbuf = (bf16_t*)(ws + (24u << 20));
    bf16_t* VTb  = (bf16_t*)(ws + (32u << 20));
    bf16_t* ctxb = (bf16_t*)(ws + (40u << 20));

    float* out  = (float*)d_out;
    float* attn = out + (size_t)B_ * L_ * D_;

    k_convert<<<2048, 256, 0, stream>>>(x, xb, (B_ * L_ * D_) / 8);
    dim3 tg4(16, 16, 4);
    k_transpose4<<<tg4, 256, 0, stream>>>(wq, wk, wv, wo, wqt, wkt, wvt, wot);

    dim3 g3(D_ / 128, (B_ * L_) / 128, 3);
    k_gemm_qkv<<<g3, 256, 0, stream>>>(xb, wqt, wkt, wvt, bq, bk, bv, Qb, Kbuf, VTb);

    k_attn<<<1024, 128, 0, stream>>>(Qb, Kbuf, VTb, ctxb, attn);

    dim3 gg(D_ / 64, (B_ * L_) / 128);
    k_gemm_o<<<gg, 256, 0, stream>>>(ctxb, wot, bo, (float*)d_out);
}